// Round 9
// baseline (187.123 us; speedup 1.0000x reference)
//
#include <hip/hip_runtime.h>
#include <hip/hip_bf16.h>
#include <math.h>

typedef __hip_bfloat16 hbf16;
typedef __attribute__((ext_vector_type(4))) float f32x4;
typedef __attribute__((ext_vector_type(8))) __bf16 bf16x8;
typedef __attribute__((ext_vector_type(4))) short short4v;

#define MFMA16(a, b, c) __builtin_amdgcn_mfma_f32_16x16x32_bf16((a), (b), (c), 0, 0, 0)

// 16x16x16 bf16 MFMA: operand frag [idx=l15][k=4*lg+i] — matches x32 C-layout.
#if __has_builtin(__builtin_amdgcn_mfma_f32_16x16x16bf16_1k)
#define MFMA16K16(a, b, c) __builtin_amdgcn_mfma_f32_16x16x16bf16_1k((a), (b), (c), 0, 0, 0)
#else
__device__ __forceinline__ f32x4 mfma16k16_asm(short4v a, short4v b, f32x4 c) {
  asm("v_mfma_f32_16x16x16_bf16 %0, %1, %2, %0" : "+v"(c) : "v"(a), "v"(b));
  return c;
}
#define MFMA16K16(a, b, c) mfma16k16_asm((a), (b), (c))
#endif

__device__ __forceinline__ void gload_lds16(const hbf16* g, hbf16* l) {
  __builtin_amdgcn_global_load_lds(
      (const __attribute__((address_space(1))) void*)g,
      (__attribute__((address_space(3))) void*)l, 16, 0, 0);
}

// ---------------- fp32 -> bf16 conversion, all six tensors, one dispatch ----
__device__ __forceinline__ void cvt4(const float* __restrict__ s, hbf16* __restrict__ d, int i) {
  float4 v = reinterpret_cast<const float4*>(s)[i];
  union { hbf16 h[4]; uint2 u; } pk;
  pk.h[0] = __float2bfloat16(v.x);
  pk.h[1] = __float2bfloat16(v.y);
  pk.h[2] = __float2bfloat16(v.z);
  pk.h[3] = __float2bfloat16(v.w);
  reinterpret_cast<uint2*>(d)[i] = pk.u;
}

__global__ __launch_bounds__(256) void cvt_all_kernel(
    const float* __restrict__ Q, const float* __restrict__ K, const float* __restrict__ V,
    const float* __restrict__ Wqk, const float* __restrict__ Wv, const float* __restrict__ Wout,
    hbf16* __restrict__ Qb, hbf16* __restrict__ Kb, hbf16* __restrict__ Vb,
    hbf16* __restrict__ Wqkb, hbf16* __restrict__ Wvb, hbf16* __restrict__ Woutb,
    int n4big, int n4w) {
  int stride = gridDim.x * blockDim.x;
  for (int i = blockIdx.x * blockDim.x + threadIdx.x; i < n4big; i += stride) {
    cvt4(Q, Qb, i);
    cvt4(K, Kb, i);
    cvt4(V, Vb, i);
    if (i < n4w) {
      cvt4(Wqk, Wqkb, i);
      cvt4(Wv, Wvb, i);
      cvt4(Wout, Woutb, i);
    }
  }
}

// ---------------- 64x128 bf16 GEMM core, 2-phase double-buffered ------------
// A MxK row-major, B NxK row-major (== B^T). 4 waves; wave w owns cols
// [w*32, w*32+32). One barrier per k-step; next tile staged before compute.
__device__ __forceinline__ void stage_a64(const hbf16* __restrict__ A, int K, int bm, int k0,
                                          hbf16* Alds, int wave, int lane) {
  const int row = wave * 16 + (lane >> 2);
  gload_lds16(A + (size_t)(bm * 64 + row) * K + k0 + (lane & 3) * 8, Alds + wave * 512);
}
__device__ __forceinline__ void stage_b128(const hbf16* __restrict__ B, int K, int bn, int k0,
                                           hbf16* Blds, int wave, int lane) {
#pragma unroll
  for (int i = 0; i < 2; ++i) {
    const int row = wave * 32 + i * 16 + (lane >> 2);
    gload_lds16(B + (size_t)(bn * 128 + row) * K + k0 + (lane & 3) * 8,
                Blds + wave * 1024 + i * 512);
  }
}

__device__ __forceinline__ void gemm_core_2ph(
    const hbf16* __restrict__ A, const hbf16* __restrict__ B, int K, int bm, int bn,
    hbf16* Alds /*2*2048*/, hbf16* Blds /*2*4096*/, f32x4 (&acc)[4][2]) {
  const int tid = threadIdx.x;
  const int lane = tid & 63;
  const int wave = tid >> 6;
  const int l15 = lane & 15, lg = lane >> 4;
  const int nt = K >> 5;
  stage_a64(A, K, bm, 0, Alds, wave, lane);
  stage_b128(B, K, bn, 0, Blds, wave, lane);
  __syncthreads();
  int cur = 0;
  for (int t = 0; t < nt; ++t) {
    if (t + 1 < nt) {  // prefetch next k-tile into the other buffer
      stage_a64(A, K, bm, (t + 1) * 32, Alds + (cur ^ 1) * 2048, wave, lane);
      stage_b128(B, K, bn, (t + 1) * 32, Blds + (cur ^ 1) * 4096, wave, lane);
    }
    bf16x8 af[4], bfv[2];
#pragma unroll
    for (int m = 0; m < 4; ++m)
      af[m] = *reinterpret_cast<const bf16x8*>(&Alds[cur * 2048 + (m * 16 + l15) * 32 + lg * 8]);
#pragma unroll
    for (int n = 0; n < 2; ++n)
      bfv[n] = *reinterpret_cast<const bf16x8*>(
          &Blds[cur * 4096 + (wave * 32 + n * 16 + l15) * 32 + lg * 8]);
#pragma unroll
    for (int m = 0; m < 4; ++m)
#pragma unroll
      for (int n = 0; n < 2; ++n)
        acc[m][n] = MFMA16(af[m], bfv[n], acc[m][n]);
    __syncthreads();  // staged tile landed + all waves done reading cur
    cur ^= 1;
  }
}

// ---------------- fused projections: z=0 qp (scale folded), z=1 kp, z=2 vT ---
__global__ __launch_bounds__(256) void proj_fused_kernel(
    const hbf16* __restrict__ Qb, const hbf16* __restrict__ Kb, const hbf16* __restrict__ Vb,
    const hbf16* __restrict__ Wqk, const hbf16* __restrict__ Wv,
    const float* __restrict__ bqk, const float* __restrict__ bv,
    hbf16* __restrict__ qp, hbf16* __restrict__ kp, hbf16* __restrict__ vT) {
  __shared__ __align__(16) hbf16 Alds[2 * 2048];
  __shared__ __align__(16) hbf16 Blds[2 * 4096];
  const int z = blockIdx.y;
  const int lane = threadIdx.x & 63, wave = threadIdx.x >> 6;
  const int l15 = lane & 15, lg = lane >> 4;

  f32x4 acc[4][2];
  const f32x4 zero = {0.f, 0.f, 0.f, 0.f};
#pragma unroll
  for (int m = 0; m < 4; ++m)
#pragma unroll
    for (int n = 0; n < 2; ++n) acc[m][n] = zero;

  if (z < 2) {
    const hbf16* A = z ? Kb : Qb;
    hbf16* outp = z ? kp : qp;
    const int bm = blockIdx.x & 63, bn = blockIdx.x >> 6;  // 64 x 4
    gemm_core_2ph(A, Wqk, 512, bm, bn, Alds, Blds, acc);
    // (1/sqrt(D)) * log2(e) folded into q so attention uses exp2 directly
    const float qscale = z ? 1.0f : 0.125f * 1.4426950408889634f;
    const int row0 = bm * 64;
    const int col0 = bn * 128 + wave * 32;
#pragma unroll
    for (int m = 0; m < 4; ++m) {
#pragma unroll
      for (int n = 0; n < 2; ++n) {
        const int col = col0 + n * 16 + l15;
        const float bsv = bqk[col];
#pragma unroll
        for (int j = 0; j < 4; ++j) {
          const int row = row0 + m * 16 + lg * 4 + j;
          outp[(size_t)row * 512 + col] = __float2bfloat16((acc[m][n][j] + bsv) * qscale);
        }
      }
    }
  } else {
    // v[s][e] = Wv[e][:] . Vb[s][:] + bv[e]; store vT[h][d][p], FLAT-reshape
    // head split: h = s>>9, p = ((s&511)<<3) + (e>>6), d = e&63.
    const int bm = blockIdx.x >> 5;   // e-tiles (8)
    const int bn = blockIdx.x & 31;   // s-tiles (32)
    gemm_core_2ph(Wv, Vb, 512, bm, bn, Alds, Blds, acc);
    const int row0 = bm * 64;
    const int col0 = bn * 128 + wave * 32;
#pragma unroll
    for (int m = 0; m < 4; ++m) {
#pragma unroll
      for (int n = 0; n < 2; ++n) {
        const int col = col0 + n * 16 + l15;          // s
#pragma unroll
        for (int j = 0; j < 4; ++j) {
          const int row = row0 + m * 16 + lg * 4 + j; // e
          const int h = col >> 9;
          const int p = ((col & 511) << 3) + (row >> 6);
          const int d = row & 63;
          vT[(size_t)h * 262144 + (size_t)d * 4096 + p] =
              __float2bfloat16(acc[m][n][j] + bv[row]);
        }
      }
    }
  }
}

// ---------------- final GEMM: fp32 output (64x128 tiles, 256 blocks) --------
__global__ __launch_bounds__(256) void out_gemm_kernel(
    const hbf16* __restrict__ A, const hbf16* __restrict__ B, const float* __restrict__ bias,
    float* __restrict__ out) {
  __shared__ __align__(16) hbf16 Alds[2 * 2048];
  __shared__ __align__(16) hbf16 Blds[2 * 4096];
  const int bm = blockIdx.x & 63, bn = blockIdx.x >> 6;  // 64 x 4
  const int lane = threadIdx.x & 63, wave = threadIdx.x >> 6;
  const int l15 = lane & 15, lg = lane >> 4;
  f32x4 acc[4][2];
  const f32x4 zero = {0.f, 0.f, 0.f, 0.f};
#pragma unroll
  for (int m = 0; m < 4; ++m)
#pragma unroll
    for (int n = 0; n < 2; ++n) acc[m][n] = zero;

  gemm_core_2ph(A, B, 512, bm, bn, Alds, Blds, acc);

  const int row0 = bm * 64;
  const int col0 = bn * 128 + wave * 32;
#pragma unroll
  for (int m = 0; m < 4; ++m) {
#pragma unroll
    for (int n = 0; n < 2; ++n) {
      const int col = col0 + n * 16 + l15;
      const float bsv = bias[col];
#pragma unroll
      for (int j = 0; j < 4; ++j) {
        const int row = row0 + m * 16 + lg * 4 + j;
        out[(size_t)row * 512 + col] = acc[m][n][j] + bsv;
      }
    }
  }
}

// ---------------- flash attention (r8 structure, unchanged math) ------------
__device__ __forceinline__ void stage64(const hbf16* __restrict__ g, int gstride,
                                        hbf16* tile, int wave, int lane) {
#pragma unroll
  for (int ii = 0; ii < 2; ++ii) {
    const int i = wave * 2 + ii;
    const int row = i * 8 + (lane >> 3);
    const int ce = ((lane & 7) ^ (lane >> 3)) << 3;  // element offset, swizzled
    gload_lds16(g + (size_t)row * gstride + ce, tile + i * 512);
  }
}

template <bool DIRECT>
__global__ __launch_bounds__(256, 4) void attn_kernel4(
    const hbf16* __restrict__ qp, const hbf16* __restrict__ kp,
    const hbf16* __restrict__ vT, hbf16* __restrict__ ao,
    float* __restrict__ Opart, float* __restrict__ Lpart,
    int kv_per_split, int nwg) {
  // bijective XCD swizzle (nwg % 8 == 0)
  const int lin = blockIdx.x + 32 * (blockIdx.y + 8 * blockIdx.z);
  const int chunk = nwg >> 3;
  const int swz = (lin & 7) * chunk + (lin >> 3);
  const int qt = swz & 31;
  const int h = (swz >> 5) & 7;
  const int split = swz >> 8;

  const hbf16* qh = qp + (size_t)h * 262144;
  const hbf16* kh = kp + (size_t)h * 262144;
  const hbf16* vh = vT + (size_t)h * 262144;

  const int lane = threadIdx.x & 63, wave = threadIdx.x >> 6;
  const int l15 = lane & 15, lg = lane >> 4;
  const int qrow0 = qt * 128 + wave * 32;
  const int kv0 = split * kv_per_split;
  const int nkt = kv_per_split >> 6;

  __shared__ __align__(16) hbf16 Kt[2][4096];  // [kv][d], src-swizzled
  __shared__ __align__(16) hbf16 Vt[2][4096];  // [d][kv], src-swizzled

  // Q fragments (2 row-blocks x 64 d); used as the x32 MFMA second operand
  bf16x8 qf[2][2];
#pragma unroll
  for (int rb = 0; rb < 2; ++rb)
#pragma unroll
    for (int dc = 0; dc < 2; ++dc)
      qf[rb][dc] = *reinterpret_cast<const bf16x8*>(
          &qh[(size_t)(qrow0 + rb * 16 + l15) * 64 + dc * 32 + lg * 8]);

  float lsum[2] = {0.f, 0.f};  // per-lane row sum for q = l15 (+rb*16)
  f32x4 oaccT[2][4];
  const f32x4 zero = {0.f, 0.f, 0.f, 0.f};
#pragma unroll
  for (int rb = 0; rb < 2; ++rb)
#pragma unroll
    for (int db = 0; db < 4; ++db) oaccT[rb][db] = zero;

  stage64(kh + (size_t)kv0 * 64, 64, Kt[0], wave, lane);
  stage64(vh + kv0, 4096, Vt[0], wave, lane);
  __syncthreads();

  int cur = 0;
  for (int t = 0; t < nkt; ++t) {
    if (t + 1 < nkt) {
      const int kb = kv0 + (t + 1) * 64;
      stage64(kh + (size_t)kb * 64, 64, Kt[cur ^ 1], wave, lane);
      stage64(vh + kb, 4096, Vt[cur ^ 1], wave, lane);
    }
    const hbf16* Kc = Kt[cur];
    const hbf16* Vc = Vt[cur];

    // swapped QK^T: s[rb][cb] = P^T[kv=16cb+4lg+j][q=l15] (pre-exp)
    f32x4 s[2][4];
#pragma unroll
    for (int rb = 0; rb < 2; ++rb)
#pragma unroll
      for (int cb = 0; cb < 4; ++cb) s[rb][cb] = zero;
#pragma unroll
    for (int cb = 0; cb < 4; ++cb) {
      const int krow = cb * 16 + l15;
      const int sw = l15 & 7;
#pragma unroll
      for (int dc = 0; dc < 2; ++dc) {
        bf16x8 kf = *reinterpret_cast<const bf16x8*>(
            &Kc[krow * 64 + (((dc * 4 + lg) ^ sw) << 3)]);
#pragma unroll
        for (int rb = 0; rb < 2; ++rb) s[rb][cb] = MFMA16(kf, qf[rb][dc], s[rb][cb]);
      }
    }

    // P = exp2(S) in-register; pack to 16x16x16 fragments (no shuffles)
    short4v pb[2][4];
#pragma unroll
    for (int rb = 0; rb < 2; ++rb)
#pragma unroll
      for (int cb = 0; cb < 4; ++cb) {
        const float p0 = exp2f(s[rb][cb][0]);
        const float p1 = exp2f(s[rb][cb][1]);
        const float p2 = exp2f(s[rb][cb][2]);
        const float p3 = exp2f(s[rb][cb][3]);
        lsum[rb] += (p0 + p1) + (p2 + p3);
        union { hbf16 h[4]; short4v v; } pk;
        pk.h[0] = __float2bfloat16(p0);
        pk.h[1] = __float2bfloat16(p1);
        pk.h[2] = __float2bfloat16(p2);
        pk.h[3] = __float2bfloat16(p3);
        pb[rb][cb] = pk.v;
      }

    // PV as O^T = V^T . P^T  (16x16x16), V^T frags read once per (db,cb)
#pragma unroll
    for (int db = 0; db < 4; ++db) {
      const int d = db * 16 + l15;
      const int swd = d & 7;
#pragma unroll
      for (int cb = 0; cb < 4; ++cb) {
        short4v vf = *reinterpret_cast<const short4v*>(
            &Vc[d * 64 + (((2 * cb + (lg >> 1)) ^ swd) << 3) + ((lg & 1) << 2)]);
#pragma unroll
        for (int rb = 0; rb < 2; ++rb)
          oaccT[rb][db] = MFMA16K16(vf, pb[rb][cb], oaccT[rb][db]);
      }
    }
    __syncthreads();
    cur ^= 1;
  }

  // epilogue: full row sums (sum the 4 lane-group partials; all lanes get it)
#pragma unroll
  for (int rb = 0; rb < 2; ++rb) {
    lsum[rb] += __shfl_xor(lsum[rb], 16);
    lsum[rb] += __shfl_xor(lsum[rb], 32);
  }
  if (DIRECT) {
    hbf16* oh = ao + (size_t)h * 262144;
#pragma unroll
    for (int rb = 0; rb < 2; ++rb) {
      const float inv = 1.f / lsum[rb];
      const int row = qrow0 + rb * 16 + l15;
#pragma unroll
      for (int db = 0; db < 4; ++db) {
        union { hbf16 h[4]; uint2 u; } pk;
#pragma unroll
        for (int j = 0; j < 4; ++j) pk.h[j] = __float2bfloat16(oaccT[rb][db][j] * inv);
        *reinterpret_cast<uint2*>(&oh[(size_t)row * 64 + db * 16 + lg * 4]) = pk.u;
      }
    }
  } else {
    const size_t hrow0 = (size_t)split * 32768 + (size_t)h * 4096;
#pragma unroll
    for (int rb = 0; rb < 2; ++rb) {
      const int row = qrow0 + rb * 16 + l15;
#pragma unroll
      for (int db = 0; db < 4; ++db) {
        float4 v;
        v.x = oaccT[rb][db][0]; v.y = oaccT[rb][db][1];
        v.z = oaccT[rb][db][2]; v.w = oaccT[rb][db][3];
        *reinterpret_cast<float4*>(&Opart[(hrow0 + row) * 64 + db * 16 + lg * 4]) = v;
      }
      if (lg == 0) Lpart[hrow0 + row] = lsum[rb];
    }
  }
}

// ---------------- combine split partials -> bf16 attention output -----------
__global__ __launch_bounds__(256) void attn_combine_kernel(
    const float* __restrict__ Opart, const float* __restrict__ Lpart,
    hbf16* __restrict__ ao, int splits) {
  const int t = threadIdx.x;
  const int hrow = blockIdx.x * 64 + (t >> 2);
  const int d0 = (t & 3) * 16;
  float denom = 0.f;
  for (int s = 0; s < splits; ++s) denom += Lpart[s * 32768 + hrow];
  const float inv = 1.f / denom;
  float4 acc[4] = {};
  for (int s = 0; s < splits; ++s) {
    const float4* p = reinterpret_cast<const float4*>(
        Opart + ((size_t)s * 32768 + hrow) * 64 + d0);
#pragma unroll
    for (int i = 0; i < 4; ++i) {
      float4 v = p[i];
      acc[i].x += v.x; acc[i].y += v.y; acc[i].z += v.z; acc[i].w += v.w;
    }
  }
  union { hbf16 h[16]; uint4 u[2]; } pk;
#pragma unroll
  for (int i = 0; i < 4; ++i) {
    pk.h[i * 4 + 0] = __float2bfloat16(acc[i].x * inv);
    pk.h[i * 4 + 1] = __float2bfloat16(acc[i].y * inv);
    pk.h[i * 4 + 2] = __float2bfloat16(acc[i].z * inv);
    pk.h[i * 4 + 3] = __float2bfloat16(acc[i].w * inv);
  }
  uint4* dst = reinterpret_cast<uint4*>(ao + (size_t)hrow * 64 + d0);
  dst[0] = pk.u[0];
  dst[1] = pk.u[1];
}

// ---------------- launch -----------------------------------------------------
extern "C" void kernel_launch(void* const* d_in, const int* in_sizes, int n_in,
                              void* d_out, int out_size, void* d_ws, size_t ws_size,
                              hipStream_t stream) {
  const float* Q = (const float*)d_in[0];
  const float* K = (const float*)d_in[1];
  const float* V = (const float*)d_in[2];
  const float* Wqk = (const float*)d_in[3];
  const float* bqk = (const float*)d_in[4];
  const float* Wv = (const float*)d_in[5];
  const float* bv = (const float*)d_in[6];
  const float* Wout = (const float*)d_in[7];
  const float* bout = (const float*)d_in[8];
  float* out = (float*)d_out;

  const size_t NE = (size_t)4096 * 512;  // 2097152
  const size_t WE = (size_t)512 * 512;   // 262144
  hbf16* ws = (hbf16*)d_ws;
  hbf16* Qb = ws;
  hbf16* Kb = Qb + NE;
  hbf16* Vb = Kb + NE;
  hbf16* Wqkb = Vb + NE;
  hbf16* Wvb = Wqkb + WE;
  hbf16* Woutb = Wvb + WE;
  hbf16* qp = Woutb + WE;
  hbf16* kp = qp + NE;
  hbf16* vT = kp + NE;
  hbf16* ao = vT + NE;

  // split-KV partial buffers AFTER the base region, only if ws_size covers them
  const size_t base_bytes = (((size_t)(7 * NE + 3 * WE) * 2) + 255) & ~(size_t)255;
  const size_t per_split_bytes = ((size_t)32768 * 64 + 32768) * 4;  // ~8.5 MB
  int splits = 1;
  if (ws_size >= base_bytes + 8 * per_split_bytes) splits = 8;
  else if (ws_size >= base_bytes + 4 * per_split_bytes) splits = 4;
  else if (ws_size >= base_bytes + 2 * per_split_bytes) splits = 2;
  float* Opart = (float*)((char*)d_ws + base_bytes);
  float* Lpart = Opart + (size_t)splits * 32768 * 64;

  cvt_all_kernel<<<2048, 256, 0, stream>>>(Q, K, V, Wqk, Wv, Wout,
                                           Qb, Kb, Vb, Wqkb, Wvb, Woutb,
                                           (int)(NE / 4), (int)(WE / 4));
  proj_fused_kernel<<<dim3(256, 3), 256, 0, stream>>>(Qb, Kb, Vb, Wqkb, Wvb, bqk, bv,
                                                      qp, kp, vT);
  if (splits == 1) {
    attn_kernel4<true><<<dim3(32, 8, 1), 256, 0, stream>>>(
        qp, kp, vT, ao, nullptr, nullptr, 4096, 256);
  } else {
    attn_kernel4<false><<<dim3(32, 8, splits), 256, 0, stream>>>(
        qp, kp, vT, nullptr, Opart, Lpart, 4096 / splits, 256 * splits);
    attn_combine_kernel<<<512, 256, 0, stream>>>(Opart, Lpart, ao, splits);
  }
  out_gemm_kernel<<<256, 256, 0, stream>>>(ao, Woutb, bout, out);
}

// Round 10
// 180.565 us; speedup vs baseline: 1.0363x; 1.0363x over previous
//
#include <hip/hip_runtime.h>
#include <hip/hip_bf16.h>
#include <math.h>

typedef __hip_bfloat16 hbf16;
typedef __attribute__((ext_vector_type(4))) float f32x4;
typedef __attribute__((ext_vector_type(8))) __bf16 bf16x8;
typedef __attribute__((ext_vector_type(4))) short short4v;

#define MFMA16(a, b, c) __builtin_amdgcn_mfma_f32_16x16x32_bf16((a), (b), (c), 0, 0, 0)

// 16x16x16 bf16 MFMA: operand frag [idx=l15][k=4*lg+i] — matches x32 C-layout.
#if __has_builtin(__builtin_amdgcn_mfma_f32_16x16x16bf16_1k)
#define MFMA16K16(a, b, c) __builtin_amdgcn_mfma_f32_16x16x16bf16_1k((a), (b), (c), 0, 0, 0)
#else
__device__ __forceinline__ f32x4 mfma16k16_asm(short4v a, short4v b, f32x4 c) {
  asm("v_mfma_f32_16x16x16_bf16 %0, %1, %2, %0" : "+v"(c) : "v"(a), "v"(b));
  return c;
}
#define MFMA16K16(a, b, c) mfma16k16_asm((a), (b), (c))
#endif

__device__ __forceinline__ void gload_lds16(const hbf16* g, hbf16* l) {
  __builtin_amdgcn_global_load_lds(
      (const __attribute__((address_space(1))) void*)g,
      (__attribute__((address_space(3))) void*)l, 16, 0, 0);
}

// -------- fp32 reg-staging helpers (fuses fp32->bf16 cvt into GEMM) ---------
struct F8 { float4 x, y; };
__device__ __forceinline__ F8 load8(const float* p) {
  F8 r;
  r.x = *reinterpret_cast<const float4*>(p);
  r.y = *reinterpret_cast<const float4*>(p + 4);
  return r;
}
__device__ __forceinline__ uint4 cvt8(const F8& f) {
  union { hbf16 h[8]; uint4 u; } pk;
  pk.h[0] = __float2bfloat16(f.x.x); pk.h[1] = __float2bfloat16(f.x.y);
  pk.h[2] = __float2bfloat16(f.x.z); pk.h[3] = __float2bfloat16(f.x.w);
  pk.h[4] = __float2bfloat16(f.y.x); pk.h[5] = __float2bfloat16(f.y.y);
  pk.h[6] = __float2bfloat16(f.y.z); pk.h[7] = __float2bfloat16(f.y.w);
  return pk.u;
}

// ---------------- 64x128 GEMM cores, 2-phase double-buffered ----------------
// A MxK, B NxK row-major (B^T math). 4 waves; wave w owns cols [w*32,w*32+32).
// One barrier per k-step; loads for t+1 issued BEFORE compute(t), LDS writes
// AFTER compute(t) (T14 split: vmcnt wait hides under MFMA).

// Variant FF: A fp32, B fp32 (projection GEMMs; cvt fused).
__device__ __forceinline__ void gemm2ph_ff(
    const float* __restrict__ A, const float* __restrict__ B, int K, int bm, int bn,
    hbf16* Alds /*2*2048*/, hbf16* Blds /*2*4096*/, f32x4 (&acc)[4][2]) {
  const int tid = threadIdx.x;
  const int lane = tid & 63, wave = tid >> 6;
  const int l15 = lane & 15, lg = lane >> 4;
  const int arow = tid >> 2, ac = (tid & 3) * 8;
  const float* Ab = A + (size_t)(bm * 64 + arow) * K + ac;
  const float* Bb0 = B + (size_t)(bn * 128 + arow) * K + ac;
  const float* Bb1 = B + (size_t)(bn * 128 + 64 + arow) * K + ac;
  const int lofs = arow * 32 + ac;
  const int nt = K >> 5;

  F8 ra = load8(Ab), rb0 = load8(Bb0), rb1 = load8(Bb1);
  *reinterpret_cast<uint4*>(&Alds[lofs]) = cvt8(ra);
  *reinterpret_cast<uint4*>(&Blds[lofs]) = cvt8(rb0);
  *reinterpret_cast<uint4*>(&Blds[2048 + lofs]) = cvt8(rb1);
  __syncthreads();

  int cur = 0;
  for (int t = 0; t < nt; ++t) {
    F8 na, nb0, nb1;
    if (t + 1 < nt) {  // issue next-tile loads before compute
      na = load8(Ab + (t + 1) * 32);
      nb0 = load8(Bb0 + (t + 1) * 32);
      nb1 = load8(Bb1 + (t + 1) * 32);
    }
    bf16x8 af[4], bfv[2];
#pragma unroll
    for (int m = 0; m < 4; ++m)
      af[m] = *reinterpret_cast<const bf16x8*>(&Alds[cur * 2048 + (m * 16 + l15) * 32 + lg * 8]);
#pragma unroll
    for (int n = 0; n < 2; ++n)
      bfv[n] = *reinterpret_cast<const bf16x8*>(
          &Blds[cur * 4096 + (wave * 32 + n * 16 + l15) * 32 + lg * 8]);
#pragma unroll
    for (int m = 0; m < 4; ++m)
#pragma unroll
      for (int n = 0; n < 2; ++n)
        acc[m][n] = MFMA16(af[m], bfv[n], acc[m][n]);
    if (t + 1 < nt) {  // cvt+write after compute (vmcnt wait hidden)
      hbf16* Ad = Alds + (cur ^ 1) * 2048;
      hbf16* Bd = Blds + (cur ^ 1) * 4096;
      *reinterpret_cast<uint4*>(&Ad[lofs]) = cvt8(na);
      *reinterpret_cast<uint4*>(&Bd[lofs]) = cvt8(nb0);
      *reinterpret_cast<uint4*>(&Bd[2048 + lofs]) = cvt8(nb1);
    }
    __syncthreads();
    cur ^= 1;
  }
}

// Variant BF: A bf16 via global_load_lds, B fp32 reg-staged (final GEMM).
__device__ __forceinline__ void stage_a64_bf(const hbf16* __restrict__ A, int K, int bm, int k0,
                                             hbf16* Alds, int wave, int lane) {
  const int row = wave * 16 + (lane >> 2);
  gload_lds16(A + (size_t)(bm * 64 + row) * K + k0 + (lane & 3) * 8, Alds + wave * 512);
}

__device__ __forceinline__ void gemm2ph_bf(
    const hbf16* __restrict__ A, const float* __restrict__ B, int K, int bm, int bn,
    hbf16* Alds, hbf16* Blds, f32x4 (&acc)[4][2]) {
  const int tid = threadIdx.x;
  const int lane = tid & 63, wave = tid >> 6;
  const int l15 = lane & 15, lg = lane >> 4;
  const int arow = tid >> 2, ac = (tid & 3) * 8;
  const float* Bb0 = B + (size_t)(bn * 128 + arow) * K + ac;
  const float* Bb1 = B + (size_t)(bn * 128 + 64 + arow) * K + ac;
  const int lofs = arow * 32 + ac;
  const int nt = K >> 5;

  stage_a64_bf(A, K, bm, 0, Alds, wave, lane);
  F8 rb0 = load8(Bb0), rb1 = load8(Bb1);
  *reinterpret_cast<uint4*>(&Blds[lofs]) = cvt8(rb0);
  *reinterpret_cast<uint4*>(&Blds[2048 + lofs]) = cvt8(rb1);
  __syncthreads();

  int cur = 0;
  for (int t = 0; t < nt; ++t) {
    F8 nb0, nb1;
    if (t + 1 < nt) {
      stage_a64_bf(A, K, bm, (t + 1) * 32, Alds + (cur ^ 1) * 2048, wave, lane);
      nb0 = load8(Bb0 + (t + 1) * 32);
      nb1 = load8(Bb1 + (t + 1) * 32);
    }
    bf16x8 af[4], bfv[2];
#pragma unroll
    for (int m = 0; m < 4; ++m)
      af[m] = *reinterpret_cast<const bf16x8*>(&Alds[cur * 2048 + (m * 16 + l15) * 32 + lg * 8]);
#pragma unroll
    for (int n = 0; n < 2; ++n)
      bfv[n] = *reinterpret_cast<const bf16x8*>(
          &Blds[cur * 4096 + (wave * 32 + n * 16 + l15) * 32 + lg * 8]);
#pragma unroll
    for (int m = 0; m < 4; ++m)
#pragma unroll
      for (int n = 0; n < 2; ++n)
        acc[m][n] = MFMA16(af[m], bfv[n], acc[m][n]);
    if (t + 1 < nt) {
      hbf16* Bd = Blds + (cur ^ 1) * 4096;
      *reinterpret_cast<uint4*>(&Bd[lofs]) = cvt8(nb0);
      *reinterpret_cast<uint4*>(&Bd[2048 + lofs]) = cvt8(nb1);
    }
    __syncthreads();
    cur ^= 1;
  }
}

// ---------------- fused projections (cvt folded in): z=0 qp, z=1 kp, z=2 vT --
__global__ __launch_bounds__(256) void proj_fused_kernel(
    const float* __restrict__ Q, const float* __restrict__ K, const float* __restrict__ V,
    const float* __restrict__ Wqk, const float* __restrict__ Wv,
    const float* __restrict__ bqk, const float* __restrict__ bv,
    hbf16* __restrict__ qp, hbf16* __restrict__ kp, hbf16* __restrict__ vT) {
  __shared__ __align__(16) hbf16 Alds[2 * 2048];
  __shared__ __align__(16) hbf16 Blds[2 * 4096];
  const int z = blockIdx.y;
  const int lane = threadIdx.x & 63, wave = threadIdx.x >> 6;
  const int l15 = lane & 15, lg = lane >> 4;

  f32x4 acc[4][2];
  const f32x4 zero = {0.f, 0.f, 0.f, 0.f};
#pragma unroll
  for (int m = 0; m < 4; ++m)
#pragma unroll
    for (int n = 0; n < 2; ++n) acc[m][n] = zero;

  if (z < 2) {
    const float* A = z ? K : Q;
    hbf16* outp = z ? kp : qp;
    const int bm = blockIdx.x & 63, bn = blockIdx.x >> 6;  // 64 x 4
    gemm2ph_ff(A, Wqk, 512, bm, bn, Alds, Blds, acc);
    // (1/sqrt(D)) * log2(e) folded into q so attention uses exp2 directly
    const float qscale = z ? 1.0f : 0.125f * 1.4426950408889634f;
    const int row0 = bm * 64;
    const int col0 = bn * 128 + wave * 32;
#pragma unroll
    for (int m = 0; m < 4; ++m) {
#pragma unroll
      for (int n = 0; n < 2; ++n) {
        const int col = col0 + n * 16 + l15;
        const float bsv = bqk[col];
#pragma unroll
        for (int j = 0; j < 4; ++j) {
          const int row = row0 + m * 16 + lg * 4 + j;
          outp[(size_t)row * 512 + col] = __float2bfloat16((acc[m][n][j] + bsv) * qscale);
        }
      }
    }
  } else {
    // v[s][e] = Wv[e][:] . V[s][:] + bv[e]; store vT[h][d][p], FLAT-reshape
    // head split: h = s>>9, p = ((s&511)<<3) + (e>>6), d = e&63.
    const int bm = blockIdx.x >> 5;   // e-tiles (8)
    const int bn = blockIdx.x & 31;   // s-tiles (32)
    gemm2ph_ff(Wv, V, 512, bm, bn, Alds, Blds, acc);
    const int row0 = bm * 64;
    const int col0 = bn * 128 + wave * 32;
#pragma unroll
    for (int m = 0; m < 4; ++m) {
#pragma unroll
      for (int n = 0; n < 2; ++n) {
        const int col = col0 + n * 16 + l15;          // s
#pragma unroll
        for (int j = 0; j < 4; ++j) {
          const int row = row0 + m * 16 + lg * 4 + j; // e
          const int h = col >> 9;
          const int p = ((col & 511) << 3) + (row >> 6);
          const int d = row & 63;
          vT[(size_t)h * 262144 + (size_t)d * 4096 + p] =
              __float2bfloat16(acc[m][n][j] + bv[row]);
        }
      }
    }
  }
}

// ---------------- final GEMM: fp32 out, A=ao bf16, B=Wout fp32 --------------
__global__ __launch_bounds__(256) void out_gemm_kernel(
    const hbf16* __restrict__ A, const float* __restrict__ B, const float* __restrict__ bias,
    float* __restrict__ out) {
  __shared__ __align__(16) hbf16 Alds[2 * 2048];
  __shared__ __align__(16) hbf16 Blds[2 * 4096];
  const int bm = blockIdx.x & 63, bn = blockIdx.x >> 6;  // 64 x 4
  const int lane = threadIdx.x & 63, wave = threadIdx.x >> 6;
  const int l15 = lane & 15, lg = lane >> 4;
  f32x4 acc[4][2];
  const f32x4 zero = {0.f, 0.f, 0.f, 0.f};
#pragma unroll
  for (int m = 0; m < 4; ++m)
#pragma unroll
    for (int n = 0; n < 2; ++n) acc[m][n] = zero;

  gemm2ph_bf(A, B, 512, bm, bn, Alds, Blds, acc);

  const int row0 = bm * 64;
  const int col0 = bn * 128 + wave * 32;
#pragma unroll
  for (int m = 0; m < 4; ++m) {
#pragma unroll
    for (int n = 0; n < 2; ++n) {
      const int col = col0 + n * 16 + l15;
      const float bsv = bias[col];
#pragma unroll
      for (int j = 0; j < 4; ++j) {
        const int row = row0 + m * 16 + lg * 4 + j;
        out[(size_t)row * 512 + col] = acc[m][n][j] + bsv;
      }
    }
  }
}

// ---------------- flash attention (r8 structure, unchanged math) ------------
__device__ __forceinline__ void stage64(const hbf16* __restrict__ g, int gstride,
                                        hbf16* tile, int wave, int lane) {
#pragma unroll
  for (int ii = 0; ii < 2; ++ii) {
    const int i = wave * 2 + ii;
    const int row = i * 8 + (lane >> 3);
    const int ce = ((lane & 7) ^ (lane >> 3)) << 3;  // element offset, swizzled
    gload_lds16(g + (size_t)row * gstride + ce, tile + i * 512);
  }
}

template <bool DIRECT>
__global__ __launch_bounds__(256, 4) void attn_kernel4(
    const hbf16* __restrict__ qp, const hbf16* __restrict__ kp,
    const hbf16* __restrict__ vT, hbf16* __restrict__ ao,
    float* __restrict__ Opart, float* __restrict__ Lpart,
    int kv_per_split, int nwg) {
  // bijective XCD swizzle (nwg % 8 == 0)
  const int lin = blockIdx.x + 32 * (blockIdx.y + 8 * blockIdx.z);
  const int chunk = nwg >> 3;
  const int swz = (lin & 7) * chunk + (lin >> 3);
  const int qt = swz & 31;
  const int h = (swz >> 5) & 7;
  const int split = swz >> 8;

  const hbf16* qh = qp + (size_t)h * 262144;
  const hbf16* kh = kp + (size_t)h * 262144;
  const hbf16* vh = vT + (size_t)h * 262144;

  const int lane = threadIdx.x & 63, wave = threadIdx.x >> 6;
  const int l15 = lane & 15, lg = lane >> 4;
  const int qrow0 = qt * 128 + wave * 32;
  const int kv0 = split * kv_per_split;
  const int nkt = kv_per_split >> 6;

  __shared__ __align__(16) hbf16 Kt[2][4096];  // [kv][d], src-swizzled
  __shared__ __align__(16) hbf16 Vt[2][4096];  // [d][kv], src-swizzled

  // Q fragments (2 row-blocks x 64 d); used as the x32 MFMA second operand
  bf16x8 qf[2][2];
#pragma unroll
  for (int rb = 0; rb < 2; ++rb)
#pragma unroll
    for (int dc = 0; dc < 2; ++dc)
      qf[rb][dc] = *reinterpret_cast<const bf16x8*>(
          &qh[(size_t)(qrow0 + rb * 16 + l15) * 64 + dc * 32 + lg * 8]);

  float lsum[2] = {0.f, 0.f};  // per-lane row sum for q = l15 (+rb*16)
  f32x4 oaccT[2][4];
  const f32x4 zero = {0.f, 0.f, 0.f, 0.f};
#pragma unroll
  for (int rb = 0; rb < 2; ++rb)
#pragma unroll
    for (int db = 0; db < 4; ++db) oaccT[rb][db] = zero;

  stage64(kh + (size_t)kv0 * 64, 64, Kt[0], wave, lane);
  stage64(vh + kv0, 4096, Vt[0], wave, lane);
  __syncthreads();

  int cur = 0;
  for (int t = 0; t < nkt; ++t) {
    if (t + 1 < nkt) {
      const int kb = kv0 + (t + 1) * 64;
      stage64(kh + (size_t)kb * 64, 64, Kt[cur ^ 1], wave, lane);
      stage64(vh + kb, 4096, Vt[cur ^ 1], wave, lane);
    }
    const hbf16* Kc = Kt[cur];
    const hbf16* Vc = Vt[cur];

    // swapped QK^T: s[rb][cb] = P^T[kv=16cb+4lg+j][q=l15] (pre-exp)
    f32x4 s[2][4];
#pragma unroll
    for (int rb = 0; rb < 2; ++rb)
#pragma unroll
      for (int cb = 0; cb < 4; ++cb) s[rb][cb] = zero;
#pragma unroll
    for (int cb = 0; cb < 4; ++cb) {
      const int krow = cb * 16 + l15;
      const int sw = l15 & 7;
#pragma unroll
      for (int dc = 0; dc < 2; ++dc) {
        bf16x8 kf = *reinterpret_cast<const bf16x8*>(
            &Kc[krow * 64 + (((dc * 4 + lg) ^ sw) << 3)]);
#pragma unroll
        for (int rb = 0; rb < 2; ++rb) s[rb][cb] = MFMA16(kf, qf[rb][dc], s[rb][cb]);
      }
    }

    // P = exp2(S) in-register; pack to 16x16x16 fragments (no shuffles)
    short4v pb[2][4];
#pragma unroll
    for (int rb = 0; rb < 2; ++rb)
#pragma unroll
      for (int cb = 0; cb < 4; ++cb) {
        const float p0 = exp2f(s[rb][cb][0]);
        const float p1 = exp2f(s[rb][cb][1]);
        const float p2 = exp2f(s[rb][cb][2]);
        const float p3 = exp2f(s[rb][cb][3]);
        lsum[rb] += (p0 + p1) + (p2 + p3);
        union { hbf16 h[4]; short4v v; } pk;
        pk.h[0] = __float2bfloat16(p0);
        pk.h[1] = __float2bfloat16(p1);
        pk.h[2] = __float2bfloat16(p2);
        pk.h[3] = __float2bfloat16(p3);
        pb[rb][cb] = pk.v;
      }

    // PV as O^T = V^T . P^T  (16x16x16), V^T frags read once per (db,cb)
#pragma unroll
    for (int db = 0; db < 4; ++db) {
      const int d = db * 16 + l15;
      const int swd = d & 7;
#pragma unroll
      for (int cb = 0; cb < 4; ++cb) {
        short4v vf = *reinterpret_cast<const short4v*>(
            &Vc[d * 64 + (((2 * cb + (lg >> 1)) ^ swd) << 3) + ((lg & 1) << 2)]);
#pragma unroll
        for (int rb = 0; rb < 2; ++rb)
          oaccT[rb][db] = MFMA16K16(vf, pb[rb][cb], oaccT[rb][db]);
      }
    }
    __syncthreads();
    cur ^= 1;
  }

  // epilogue: full row sums (sum the 4 lane-group partials; all lanes get it)
#pragma unroll
  for (int rb = 0; rb < 2; ++rb) {
    lsum[rb] += __shfl_xor(lsum[rb], 16);
    lsum[rb] += __shfl_xor(lsum[rb], 32);
  }
  if (DIRECT) {
    hbf16* oh = ao + (size_t)h * 262144;
#pragma unroll
    for (int rb = 0; rb < 2; ++rb) {
      const float inv = 1.f / lsum[rb];
      const int row = qrow0 + rb * 16 + l15;
#pragma unroll
      for (int db = 0; db < 4; ++db) {
        union { hbf16 h[4]; uint2 u; } pk;
#pragma unroll
        for (int j = 0; j < 4; ++j) pk.h[j] = __float2bfloat16(oaccT[rb][db][j] * inv);
        *reinterpret_cast<uint2*>(&oh[(size_t)row * 64 + db * 16 + lg * 4]) = pk.u;
      }
    }
  } else {
    const size_t hrow0 = (size_t)split * 32768 + (size_t)h * 4096;
#pragma unroll
    for (int rb = 0; rb < 2; ++rb) {
      const int row = qrow0 + rb * 16 + l15;
#pragma unroll
      for (int db = 0; db < 4; ++db) {
        float4 v;
        v.x = oaccT[rb][db][0]; v.y = oaccT[rb][db][1];
        v.z = oaccT[rb][db][2]; v.w = oaccT[rb][db][3];
        *reinterpret_cast<float4*>(&Opart[(hrow0 + row) * 64 + db * 16 + lg * 4]) = v;
      }
      if (lg == 0) Lpart[hrow0 + row] = lsum[rb];
    }
  }
}

// ---------------- combine split partials -> bf16 attention output -----------
__global__ __launch_bounds__(256) void attn_combine_kernel(
    const float* __restrict__ Opart, const float* __restrict__ Lpart,
    hbf16* __restrict__ ao, int splits) {
  const int t = threadIdx.x;
  const int hrow = blockIdx.x * 64 + (t >> 2);
  const int d0 = (t & 3) * 16;
  float denom = 0.f;
  for (int s = 0; s < splits; ++s) denom += Lpart[s * 32768 + hrow];
  const float inv = 1.f / denom;
  float4 acc[4] = {};
  for (int s = 0; s < splits; ++s) {
    const float4* p = reinterpret_cast<const float4*>(
        Opart + ((size_t)s * 32768 + hrow) * 64 + d0);
#pragma unroll
    for (int i = 0; i < 4; ++i) {
      float4 v = p[i];
      acc[i].x += v.x; acc[i].y += v.y; acc[i].z += v.z; acc[i].w += v.w;
    }
  }
  union { hbf16 h[16]; uint4 u[2]; } pk;
#pragma unroll
  for (int i = 0; i < 4; ++i) {
    pk.h[i * 4 + 0] = __float2bfloat16(acc[i].x * inv);
    pk.h[i * 4 + 1] = __float2bfloat16(acc[i].y * inv);
    pk.h[i * 4 + 2] = __float2bfloat16(acc[i].z * inv);
    pk.h[i * 4 + 3] = __float2bfloat16(acc[i].w * inv);
  }
  uint4* dst = reinterpret_cast<uint4*>(ao + (size_t)hrow * 64 + d0);
  dst[0] = pk.u[0];
  dst[1] = pk.u[1];
}

// ---------------- launch -----------------------------------------------------
extern "C" void kernel_launch(void* const* d_in, const int* in_sizes, int n_in,
                              void* d_out, int out_size, void* d_ws, size_t ws_size,
                              hipStream_t stream) {
  const float* Q = (const float*)d_in[0];
  const float* K = (const float*)d_in[1];
  const float* V = (const float*)d_in[2];
  const float* Wqk = (const float*)d_in[3];
  const float* bqk = (const float*)d_in[4];
  const float* Wv = (const float*)d_in[5];
  const float* bv = (const float*)d_in[6];
  const float* Wout = (const float*)d_in[7];
  const float* bout = (const float*)d_in[8];
  float* out = (float*)d_out;

  const size_t NE = (size_t)4096 * 512;  // 2097152
  hbf16* ws = (hbf16*)d_ws;
  hbf16* qp = ws;
  hbf16* kp = qp + NE;
  hbf16* vT = kp + NE;
  hbf16* ao = vT + NE;

  // split-KV partial buffers AFTER the base region, only if ws_size covers them
  const size_t base_bytes = ((4 * NE * 2) + 255) & ~(size_t)255;
  const size_t per_split_bytes = ((size_t)32768 * 64 + 32768) * 4;  // ~8.5 MB
  int splits = 1;
  if (ws_size >= base_bytes + 4 * per_split_bytes) splits = 4;
  else if (ws_size >= base_bytes + 2 * per_split_bytes) splits = 2;
  float* Opart = (float*)((char*)d_ws + base_bytes);
  float* Lpart = Opart + (size_t)splits * 32768 * 64;

  proj_fused_kernel<<<dim3(256, 3), 256, 0, stream>>>(Q, K, V, Wqk, Wv, bqk, bv,
                                                      qp, kp, vT);
  if (splits == 1) {
    attn_kernel4<true><<<dim3(32, 8, 1), 256, 0, stream>>>(
        qp, kp, vT, ao, nullptr, nullptr, 4096, 256);
  } else {
    attn_kernel4<false><<<dim3(32, 8, splits), 256, 0, stream>>>(
        qp, kp, vT, nullptr, Opart, Lpart, 4096 / splits, 256 * splits);
    attn_combine_kernel<<<512, 256, 0, stream>>>(Opart, Lpart, ao, splits);
  }
  out_gemm_kernel<<<256, 256, 0, stream>>>(ao, Wout, bout, out);
}